// Round 1
// baseline (1097.626 us; speedup 1.0000x reference)
//
#include <hip/hip_runtime.h>
#include <math.h>

// SpaMamba: row-mamba (scan along W) -> col-mamba (scan along H) -> GroupNorm+SiLU
// B=8, C=128, H=64, W=64, D_INNER=256, D_STATE=16, D_CONV=4, DT_RANK=8, GROUPS=4
//
// Position index n (15 bits) decomposes as b[3] : m1[6] : m0[6].
// Row phase:  m1=h, m0=w (seq = b*64+h, t=w).  Col phase: m1=w, m0=h (seq=b*64+w, t=h).
//
// Workspace layout (floats):
//   xz    : 32768*512  = 16,777,216   (xc_pre | z)
//   xc    : 32768*256  =  8,388,608   (post-conv silu)   [stage2 overlays this in col phase]
//   dt    : 32768*256  =  8,388,608   (dt, then overwritten in-place by scan with y*silu(z))
//   bc    : 32768*32   =  1,048,576   (B[16]|C[16] per position)
//   st1   : 32768*128  =  4,194,304   (row-mamba output, (B,H,W,C))
//   stats : 64
// total ~155.2 MB

#define SILU(x) ((x) / (1.f + expf(-(x))))

// ---------------- generic tiled fp32 GEMM:  C[n][j] = sum_k A[n,k] * W[j*K+k] ----------
// A[n,k] addressed via  b*SB + m1*S1 + m0*S0 + k*SK  with n = (b<<12)|(m1<<6)|m0.
__global__ __launch_bounds__(256) void gemm_kernel(
    const float* __restrict__ A, const float* __restrict__ Wm, float* __restrict__ Cc,
    int NO, int K, int SB, int S1, int S0, int SK, int KCONTIG) {
  __shared__ __align__(16) float At[64][68];   // [k][n]
  __shared__ __align__(16) float Ws[64][68];   // [k][j]
  const int tid = threadIdx.x;
  const int n0 = blockIdx.x * 64;
  const int j0 = blockIdx.y * 64;
  const int ti = tid >> 4, tj = tid & 15;     // 16x16 thread tile, each 4x4 outputs
  const int p0 = ti * 4, q0 = tj * 4;

  float acc[4][4];
#pragma unroll
  for (int i = 0; i < 4; i++)
#pragma unroll
    for (int q = 0; q < 4; q++) acc[i][q] = 0.f;

  for (int kc = 0; kc < K; kc += 64) {
    // load A tile (64 n x 64 k), transposed into At[k][n]
#pragma unroll
    for (int i = 0; i < 16; i++) {
      int idx = tid + i * 256;
      int k_l, n_l;
      if (KCONTIG) { k_l = idx & 63; n_l = idx >> 6; }
      else         { n_l = idx & 63; k_l = idx >> 6; }
      int n = n0 + n_l;
      int b = n >> 12, m1 = (n >> 6) & 63, m0 = n & 63;
      At[k_l][n_l] = A[b * SB + m1 * S1 + m0 * S0 + (kc + k_l) * SK];
    }
    // load W tile (64 j x 64 k), transposed into Ws[k][j]
#pragma unroll
    for (int i = 0; i < 16; i++) {
      int idx = tid + i * 256;
      int k_l = idx & 63, j_l = idx >> 6;
      Ws[k_l][j_l] = Wm[(j0 + j_l) * K + kc + k_l];
    }
    __syncthreads();
#pragma unroll 16
    for (int k = 0; k < 64; k++) {
      float4 a4 = *reinterpret_cast<const float4*>(&At[k][p0]);
      float4 b4 = *reinterpret_cast<const float4*>(&Ws[k][q0]);
      const float av[4] = {a4.x, a4.y, a4.z, a4.w};
      const float bv[4] = {b4.x, b4.y, b4.z, b4.w};
#pragma unroll
      for (int i = 0; i < 4; i++)
#pragma unroll
        for (int q = 0; q < 4; q++) acc[i][q] = fmaf(av[i], bv[q], acc[i][q]);
    }
    __syncthreads();
  }
#pragma unroll
  for (int i = 0; i < 4; i++) {
    float4 v = make_float4(acc[i][0], acc[i][1], acc[i][2], acc[i][3]);
    *reinterpret_cast<float4*>(&Cc[(n0 + p0 + i) * NO + j0 + q0]) = v;
  }
}

// ---------------- causal depthwise conv (k=4) + bias + silu -----------------
__global__ __launch_bounds__(256) void conv_silu_kernel(
    const float* __restrict__ xz, const float* __restrict__ cw,
    const float* __restrict__ cb, float* __restrict__ xc) {
  int n = blockIdx.x;          // position
  int d = threadIdx.x;         // channel 0..255
  int w = n & 63;              // t within sequence
  float acc = cb[d];
  const float* cwd = cw + d * 4;
#pragma unroll
  for (int k = 0; k < 4; k++) {
    int ws = w - 3 + k;
    if (ws >= 0) acc = fmaf(xz[(n - 3 + k) * 512 + d], cwd[k], acc);
  }
  xc[n * 256 + d] = SILU(acc);
}

// ---------------- x-projection: xdbl(40) -> dt(256 softplus), B(16), C(16) ----------
__global__ __launch_bounds__(256) void xproj_kernel(
    const float* __restrict__ xc, const float* __restrict__ Wx,
    const float* __restrict__ Wdt, const float* __restrict__ bdt,
    float* __restrict__ dt, float* __restrict__ bc) {
  __shared__ float lxc[256];
  __shared__ float lpart[160];
  __shared__ float lxd[40];
  int n = blockIdx.x, t = threadIdx.x;
  lxc[t] = xc[n * 256 + t];
  __syncthreads();
  if (t < 160) {
    int j = t >> 2, q = t & 3;
    const float* wr = Wx + j * 256 + q * 64;
    const float* xr = lxc + q * 64;
    float s = 0.f;
#pragma unroll 16
    for (int i = 0; i < 64; i++) s = fmaf(xr[i], wr[i], s);
    lpart[t] = s;
  }
  __syncthreads();
  if (t < 40) lxd[t] = lpart[4 * t] + lpart[4 * t + 1] + lpart[4 * t + 2] + lpart[4 * t + 3];
  __syncthreads();
  if (t < 32) bc[n * 32 + t] = lxd[8 + t];   // B = xdbl[8:24], C = xdbl[24:40]
  float acc = bdt[t];
#pragma unroll
  for (int r = 0; r < 8; r++) acc = fmaf(lxd[r], Wdt[t * 8 + r], acc);
  // softplus, numerically stable
  dt[n * 256 + t] = fmaxf(acc, 0.f) + log1pf(expf(-fabsf(acc)));
}

// ---------------- sequential SSM scan, one thread per (seq, d) ----------------
// writes ydt[idx] = (y + xc*D) * silu(z)  in place over dt (read-before-write per thread)
__global__ __launch_bounds__(256) void scan_kernel(
    const float* dtb, const float* __restrict__ xcb, const float* __restrict__ xzb,
    const float* __restrict__ bcb, const float* __restrict__ Alog,
    const float* __restrict__ Dv, float* ydt) {
  __shared__ float lbc[64 * 32];
  int seq = blockIdx.x, d = threadIdx.x;
#pragma unroll
  for (int i = 0; i < 8; i++) lbc[d + i * 256] = bcb[seq * 2048 + d + i * 256];
  float As[16];
#pragma unroll
  for (int s = 0; s < 16; s++) As[s] = -expf(Alog[d * 16 + s]);
  float Dd = Dv[d];
  float h[16];
#pragma unroll
  for (int s = 0; s < 16; s++) h[s] = 0.f;
  __syncthreads();
  int base = seq * 64;
  for (int w = 0; w < 64; w++) {
    int idx = (base + w) * 256 + d;
    float dtv = dtb[idx];
    float xcv = xcb[idx];
    float dx = dtv * xcv;
    float yv = 0.f;
    const float* bw = lbc + w * 32;
#pragma unroll
    for (int s = 0; s < 16; s++) {
      h[s] = fmaf(h[s], expf(dtv * As[s]), dx * bw[s]);
      yv = fmaf(h[s], bw[16 + s], yv);
    }
    float zv = xzb[(base + w) * 512 + 256 + d];
    ydt[idx] = (yv + xcv * Dd) * SILU(zv);
  }
}

// ---------------- GroupNorm stats (per (b,g)), f64 accumulation ----------------
__global__ __launch_bounds__(256) void gn_stats_kernel(
    const float* __restrict__ s2, float* __restrict__ stats) {
  int b = blockIdx.x >> 2, g = blockIdx.x & 3;
  int t = threadIdx.x;
  const float* basep = s2 + b * 524288 + g * 32;
  double sum = 0.0, sumsq = 0.0;
  for (int i = t; i < 131072; i += 256) {
    int c = i & 31, sp = i >> 5;
    float v = basep[sp * 128 + c];
    sum += v;
    sumsq += (double)v * v;
  }
  __shared__ double ls[256], lq[256];
  ls[t] = sum; lq[t] = sumsq;
  __syncthreads();
  for (int o = 128; o > 0; o >>= 1) {
    if (t < o) { ls[t] += ls[t + o]; lq[t] += lq[t + o]; }
    __syncthreads();
  }
  if (t == 0) {
    double mu = ls[0] / 131072.0;
    double var = lq[0] / 131072.0 - mu * mu;
    stats[blockIdx.x * 2] = (float)mu;
    stats[blockIdx.x * 2 + 1] = (float)(1.0 / sqrt(var + 1e-5));
  }
}

// ---------------- GN apply + silu, with LDS transpose (b,w,h,c) -> (b,c,h,w) --------
__global__ __launch_bounds__(256) void gn_apply_kernel(
    const float* __restrict__ s2, const float* __restrict__ stats,
    const float* __restrict__ gamma, const float* __restrict__ beta,
    float* __restrict__ out) {
  __shared__ float tile[64 * 129];  // [w][c], pad to 129 to kill bank conflicts
  int b = blockIdx.x >> 6, hh = blockIdx.x & 63;
  int t = threadIdx.x;
  const float* src = s2 + b * 524288 + hh * 128;  // + w*8192 + c
#pragma unroll
  for (int i = 0; i < 32; i++) {
    int idx = t + i * 256;
    int c = idx & 127, w = idx >> 7;
    tile[w * 129 + c] = src[w * 8192 + c];
  }
  __syncthreads();
  float* dst = out + b * 524288 + hh * 64;        // + c*4096 + w
#pragma unroll
  for (int i = 0; i < 32; i++) {
    int idx = t + i * 256;
    int w = idx & 63, c = idx >> 6;
    int g = c >> 5;
    float mu = stats[(b * 4 + g) * 2];
    float rs = stats[(b * 4 + g) * 2 + 1];
    float v = fmaf((tile[w * 129 + c] - mu) * rs, gamma[c], beta[c]);
    dst[c * 4096 + w] = SILU(v);
  }
}

extern "C" void kernel_launch(void* const* d_in, const int* in_sizes, int n_in,
                              void* d_out, int out_size, void* d_ws, size_t ws_size,
                              hipStream_t stream) {
  const float* x = (const float*)d_in[0];
  // row weights
  const float* rWin  = (const float*)d_in[1];
  const float* rcw   = (const float*)d_in[2];
  const float* rcb   = (const float*)d_in[3];
  const float* rWx   = (const float*)d_in[4];
  const float* rWdt  = (const float*)d_in[5];
  const float* rbdt  = (const float*)d_in[6];
  const float* rAlog = (const float*)d_in[7];
  const float* rD    = (const float*)d_in[8];
  const float* rWout = (const float*)d_in[9];
  // col weights
  const float* cWin  = (const float*)d_in[10];
  const float* ccw   = (const float*)d_in[11];
  const float* ccb   = (const float*)d_in[12];
  const float* cWx   = (const float*)d_in[13];
  const float* cWdt  = (const float*)d_in[14];
  const float* cbdt  = (const float*)d_in[15];
  const float* cAlog = (const float*)d_in[16];
  const float* cD    = (const float*)d_in[17];
  const float* cWout = (const float*)d_in[18];
  const float* gamma = (const float*)d_in[19];
  const float* beta  = (const float*)d_in[20];
  float* out = (float*)d_out;

  float* ws = (float*)d_ws;
  float* xz    = ws;                    // 16,777,216
  float* xc    = xz  + 16777216;        //  8,388,608
  float* dt    = xc  + 8388608;         //  8,388,608
  float* bc    = dt  + 8388608;         //  1,048,576
  float* st1   = bc  + 1048576;         //  4,194,304
  float* stats = st1 + 4194304;         //  64
  float* st2   = xc;                    // overlay: xc is dead by the time stage2 is written

  auto run_mamba = [&](const float* A, int SB, int S1, int S0, int SK, int KCONTIG,
                       const float* Win, const float* cw, const float* cb,
                       const float* Wx, const float* Wdt, const float* bdt,
                       const float* Alog, const float* Dv, const float* Wout,
                       float* outp) {
    gemm_kernel<<<dim3(512, 8), 256, 0, stream>>>(A, Win, xz, 512, 128, SB, S1, S0, SK, KCONTIG);
    conv_silu_kernel<<<32768, 256, 0, stream>>>(xz, cw, cb, xc);
    xproj_kernel<<<32768, 256, 0, stream>>>(xc, Wx, Wdt, bdt, dt, bc);
    scan_kernel<<<512, 256, 0, stream>>>(dt, xc, xz, bc, Alog, Dv, dt);
    gemm_kernel<<<dim3(512, 2), 256, 0, stream>>>(dt, Wout, outp, 128, 256,
                                                  1048576, 16384, 256, 1, 1);
  };

  // row phase: A[n,k] = x[b,k,h,w], n=(b,h,w)
  run_mamba(x, 524288, 64, 1, 4096, 0,
            rWin, rcw, rcb, rWx, rWdt, rbdt, rAlog, rD, rWout, st1);
  // col phase: A[n,k] = st1[b,h,w,k], n=(b,w,h)
  run_mamba(st1, 524288, 128, 8192, 1, 1,
            cWin, ccw, ccb, cWx, cWdt, cbdt, cAlog, cD, cWout, st2);

  gn_stats_kernel<<<32, 256, 0, stream>>>(st2, stats);
  gn_apply_kernel<<<512, 256, 0, stream>>>(st2, stats, gamma, beta, out);
}

// Round 2
// 856.824 us; speedup vs baseline: 1.2810x; 1.2810x over previous
//
#include <hip/hip_runtime.h>
#include <math.h>

// SpaMamba: row-mamba (scan along W) -> col-mamba (scan along H) -> GroupNorm+SiLU
// B=8, C=128, H=64, W=64, D_INNER=256, D_STATE=16, D_CONV=4, DT_RANK=8, GROUPS=4
//
// Position index n (15 bits) decomposes as b[3] : m1[6] : m0[6].
// Row phase:  m1=h, m0=w (seq = b*64+h, t=w).  Col phase: m1=w, m0=h (seq=b*64+w, t=h).
//
// Workspace layout (floats):
//   xz    : 32768*512  = 16,777,216   (xc_pre | z)
//   xc    : 32768*256  =  8,388,608   (post-conv silu)   [stage2 overlays this in col phase]
//   dt    : 32768*256  =  8,388,608   (dt; scan overwrites in place with y*silu(z))
//   st1   : 32768*128  =  4,194,304   (row-mamba output (B,H,W,C); ALSO aliased by
//                                      xdbl (32768*40) in the window where st1 is dead)
//   stats : 64
// total ~151 MB

#define SILU(x) ((x) / (1.f + expf(-(x))))

// ---------------- generic tiled fp32 GEMM:  C[n][j] = sum_k A[n,k] * W[j*K+k] ----------
// A[n,k] addressed via  b*SB + m1*S1 + m0*S0 + k*SK  with n = (b<<12)|(m1<<6)|m0.
// NJ = number of valid output columns (W rows); NO = row stride of C.
__global__ __launch_bounds__(256) void gemm_kernel(
    const float* __restrict__ A, const float* __restrict__ Wm, float* __restrict__ Cc,
    int NO, int NJ, int K, int SB, int S1, int S0, int SK, int KCONTIG) {
  __shared__ __align__(16) float At[64][68];   // [k][n]
  __shared__ __align__(16) float Ws[64][68];   // [k][j]
  const int tid = threadIdx.x;
  const int n0 = blockIdx.x * 64;
  const int j0 = blockIdx.y * 64;
  const int ti = tid >> 4, tj = tid & 15;     // 16x16 thread tile, each 4x4 outputs
  const int p0 = ti * 4, q0 = tj * 4;

  float acc[4][4];
#pragma unroll
  for (int i = 0; i < 4; i++)
#pragma unroll
    for (int q = 0; q < 4; q++) acc[i][q] = 0.f;

  for (int kc = 0; kc < K; kc += 64) {
    // load A tile (64 n x 64 k), transposed into At[k][n]
#pragma unroll
    for (int i = 0; i < 16; i++) {
      int idx = tid + i * 256;
      int k_l, n_l;
      if (KCONTIG) { k_l = idx & 63; n_l = idx >> 6; }
      else         { n_l = idx & 63; k_l = idx >> 6; }
      int n = n0 + n_l;
      int b = n >> 12, m1 = (n >> 6) & 63, m0 = n & 63;
      At[k_l][n_l] = A[b * SB + m1 * S1 + m0 * S0 + (kc + k_l) * SK];
    }
    // load W tile (64 j x 64 k), transposed into Ws[k][j]; guard j >= NJ
#pragma unroll
    for (int i = 0; i < 16; i++) {
      int idx = tid + i * 256;
      int k_l = idx & 63, j_l = idx >> 6;
      Ws[k_l][j_l] = (j0 + j_l < NJ) ? Wm[(j0 + j_l) * K + kc + k_l] : 0.f;
    }
    __syncthreads();
#pragma unroll 16
    for (int k = 0; k < 64; k++) {
      float4 a4 = *reinterpret_cast<const float4*>(&At[k][p0]);
      float4 b4 = *reinterpret_cast<const float4*>(&Ws[k][q0]);
      const float av[4] = {a4.x, a4.y, a4.z, a4.w};
      const float bv[4] = {b4.x, b4.y, b4.z, b4.w};
#pragma unroll
      for (int i = 0; i < 4; i++)
#pragma unroll
        for (int q = 0; q < 4; q++) acc[i][q] = fmaf(av[i], bv[q], acc[i][q]);
    }
    __syncthreads();
  }
  if (j0 + q0 < NJ) {
#pragma unroll
    for (int i = 0; i < 4; i++) {
      float4 v = make_float4(acc[i][0], acc[i][1], acc[i][2], acc[i][3]);
      *reinterpret_cast<float4*>(&Cc[(n0 + p0 + i) * NO + j0 + q0]) = v;
    }
  }
}

// ---------------- causal depthwise conv (k=4) + bias + silu -----------------
__global__ __launch_bounds__(256) void conv_silu_kernel(
    const float* __restrict__ xz, const float* __restrict__ cw,
    const float* __restrict__ cb, float* __restrict__ xc) {
  int n = blockIdx.x;          // position
  int d = threadIdx.x;         // channel 0..255
  int w = n & 63;              // t within sequence
  float acc = cb[d];
  const float* cwd = cw + d * 4;
#pragma unroll
  for (int k = 0; k < 4; k++) {
    int ws = w - 3 + k;
    if (ws >= 0) acc = fmaf(xz[(n - 3 + k) * 512 + d], cwd[k], acc);
  }
  xc[n * 256 + d] = SILU(acc);
}

// ---------------- dt expansion: dt = softplus(xdbl[:, :8] @ Wdt.T + bdt) -----------
__global__ __launch_bounds__(256) void dt_expand_kernel(
    const float* __restrict__ xdbl, const float* __restrict__ Wdt,
    const float* __restrict__ bdt, float* __restrict__ dt) {
  __shared__ float lx[64][8];
  int n0 = blockIdx.x * 64, t = threadIdx.x;
#pragma unroll
  for (int i = 0; i < 2; i++) {
    int idx = t + i * 256;
    int n = idx >> 3, r = idx & 7;
    lx[n][r] = xdbl[(n0 + n) * 40 + r];
  }
  float w[8];
#pragma unroll
  for (int r = 0; r < 8; r++) w[r] = Wdt[t * 8 + r];
  float bb = bdt[t];
  __syncthreads();
  for (int n = 0; n < 64; n++) {
    float acc = bb;
#pragma unroll
    for (int r = 0; r < 8; r++) acc = fmaf(lx[n][r], w[r], acc);
    dt[(n0 + n) * 256 + t] = fmaxf(acc, 0.f) + log1pf(expf(-fabsf(acc)));
  }
}

// ---------------- sequential SSM scan, one thread per (seq, d) ----------------
// writes ydt[idx] = (y + xc*D) * silu(z)  in place over dt (read-before-write per thread)
// B/C come straight from xdbl rows: B = xdbl[n][8:24], C = xdbl[n][24:40]
__global__ __launch_bounds__(256) void scan_kernel(
    const float* dtb, const float* __restrict__ xcb, const float* __restrict__ xzb,
    const float* __restrict__ xdbl, const float* __restrict__ Alog,
    const float* __restrict__ Dv, float* ydt) {
  __shared__ float lbc[64 * 32];
  int seq = blockIdx.x, d = threadIdx.x;
  int base = seq * 64;
#pragma unroll
  for (int i = 0; i < 8; i++) {
    int idx = d + i * 256;
    int w = idx >> 5, s = idx & 31;
    lbc[idx] = xdbl[(base + w) * 40 + 8 + s];
  }
  float As[16];
#pragma unroll
  for (int s = 0; s < 16; s++) As[s] = -expf(Alog[d * 16 + s]);
  float Dd = Dv[d];
  float h[16];
#pragma unroll
  for (int s = 0; s < 16; s++) h[s] = 0.f;
  __syncthreads();
  for (int w = 0; w < 64; w++) {
    int idx = (base + w) * 256 + d;
    float dtv = dtb[idx];
    float xcv = xcb[idx];
    float dx = dtv * xcv;
    float yv = 0.f;
    const float* bw = lbc + w * 32;
#pragma unroll
    for (int s = 0; s < 16; s++) {
      h[s] = fmaf(h[s], expf(dtv * As[s]), dx * bw[s]);
      yv = fmaf(h[s], bw[16 + s], yv);
    }
    float zv = xzb[(base + w) * 512 + 256 + d];
    ydt[idx] = (yv + xcv * Dd) * SILU(zv);
  }
}

// ---------------- GroupNorm stats (per (b,g)), f64 accumulation ----------------
__global__ __launch_bounds__(256) void gn_stats_kernel(
    const float* __restrict__ s2, float* __restrict__ stats) {
  int b = blockIdx.x >> 2, g = blockIdx.x & 3;
  int t = threadIdx.x;
  const float* basep = s2 + b * 524288 + g * 32;
  double sum = 0.0, sumsq = 0.0;
  for (int i = t; i < 131072; i += 256) {
    int c = i & 31, sp = i >> 5;
    float v = basep[sp * 128 + c];
    sum += v;
    sumsq += (double)v * v;
  }
  __shared__ double ls[256], lq[256];
  ls[t] = sum; lq[t] = sumsq;
  __syncthreads();
  for (int o = 128; o > 0; o >>= 1) {
    if (t < o) { ls[t] += ls[t + o]; lq[t] += lq[t + o]; }
    __syncthreads();
  }
  if (t == 0) {
    double mu = ls[0] / 131072.0;
    double var = lq[0] / 131072.0 - mu * mu;
    stats[blockIdx.x * 2] = (float)mu;
    stats[blockIdx.x * 2 + 1] = (float)(1.0 / sqrt(var + 1e-5));
  }
}

// ---------------- GN apply + silu, with LDS transpose (b,w,h,c) -> (b,c,h,w) --------
__global__ __launch_bounds__(256) void gn_apply_kernel(
    const float* __restrict__ s2, const float* __restrict__ stats,
    const float* __restrict__ gamma, const float* __restrict__ beta,
    float* __restrict__ out) {
  __shared__ float tile[64 * 129];  // [w][c], pad to 129 to kill bank conflicts
  int b = blockIdx.x >> 6, hh = blockIdx.x & 63;
  int t = threadIdx.x;
  const float* src = s2 + b * 524288 + hh * 128;  // + w*8192 + c
#pragma unroll
  for (int i = 0; i < 32; i++) {
    int idx = t + i * 256;
    int c = idx & 127, w = idx >> 7;
    tile[w * 129 + c] = src[w * 8192 + c];
  }
  __syncthreads();
  float* dst = out + b * 524288 + hh * 64;        // + c*4096 + w
#pragma unroll
  for (int i = 0; i < 32; i++) {
    int idx = t + i * 256;
    int w = idx & 63, c = idx >> 6;
    int g = c >> 5;
    float mu = stats[(b * 4 + g) * 2];
    float rs = stats[(b * 4 + g) * 2 + 1];
    float v = fmaf((tile[w * 129 + c] - mu) * rs, gamma[c], beta[c]);
    dst[c * 4096 + w] = SILU(v);
  }
}

extern "C" void kernel_launch(void* const* d_in, const int* in_sizes, int n_in,
                              void* d_out, int out_size, void* d_ws, size_t ws_size,
                              hipStream_t stream) {
  const float* x = (const float*)d_in[0];
  // row weights
  const float* rWin  = (const float*)d_in[1];
  const float* rcw   = (const float*)d_in[2];
  const float* rcb   = (const float*)d_in[3];
  const float* rWx   = (const float*)d_in[4];
  const float* rWdt  = (const float*)d_in[5];
  const float* rbdt  = (const float*)d_in[6];
  const float* rAlog = (const float*)d_in[7];
  const float* rD    = (const float*)d_in[8];
  const float* rWout = (const float*)d_in[9];
  // col weights
  const float* cWin  = (const float*)d_in[10];
  const float* ccw   = (const float*)d_in[11];
  const float* ccb   = (const float*)d_in[12];
  const float* cWx   = (const float*)d_in[13];
  const float* cWdt  = (const float*)d_in[14];
  const float* cbdt  = (const float*)d_in[15];
  const float* cAlog = (const float*)d_in[16];
  const float* cD    = (const float*)d_in[17];
  const float* cWout = (const float*)d_in[18];
  const float* gamma = (const float*)d_in[19];
  const float* beta  = (const float*)d_in[20];
  float* out = (float*)d_out;

  float* ws = (float*)d_ws;
  float* xz    = ws;                    // 16,777,216
  float* xc    = xz  + 16777216;        //  8,388,608
  float* dt    = xc  + 8388608;         //  8,388,608
  float* st1   = dt  + 8388608;         //  4,194,304
  float* stats = st1 + 4194304;         //  64
  float* xdbl  = st1;                   // overlay: st1 is dead while xdbl lives
  float* st2   = xc;                    // overlay: xc is dead by the time stage2 is written

  auto run_mamba = [&](const float* A, int SB, int S1, int S0, int SK, int KCONTIG,
                       const float* Win, const float* cw, const float* cb,
                       const float* Wx, const float* Wdt, const float* bdt,
                       const float* Alog, const float* Dv, const float* Wout,
                       float* outp) {
    gemm_kernel<<<dim3(512, 8), 256, 0, stream>>>(A, Win, xz, 512, 512, 128,
                                                  SB, S1, S0, SK, KCONTIG);
    conv_silu_kernel<<<32768, 256, 0, stream>>>(xz, cw, cb, xc);
    // xdbl = xc @ Wx.T   (M=32768, N=40, K=256); xc is n-major contiguous
    gemm_kernel<<<dim3(512, 1), 256, 0, stream>>>(xc, Wx, xdbl, 40, 40, 256,
                                                  1048576, 16384, 256, 1, 1);
    dt_expand_kernel<<<512, 256, 0, stream>>>(xdbl, Wdt, bdt, dt);
    scan_kernel<<<512, 256, 0, stream>>>(dt, xc, xz, xdbl, Alog, Dv, dt);
    gemm_kernel<<<dim3(512, 2), 256, 0, stream>>>(dt, Wout, outp, 128, 128, 256,
                                                  1048576, 16384, 256, 1, 1);
  };

  // row phase: A[n,k] = x[b,k,h,w], n=(b,h,w)
  run_mamba(x, 524288, 64, 1, 4096, 0,
            rWin, rcw, rcb, rWx, rWdt, rbdt, rAlog, rD, rWout, st1);
  // col phase: A[n,k] = st1[b,h,w,k], n=(b,w,h)
  run_mamba(st1, 524288, 128, 8192, 1, 1,
            cWin, ccw, ccb, cWx, cWdt, cbdt, cAlog, cD, cWout, st2);

  gn_stats_kernel<<<32, 256, 0, stream>>>(st2, stats);
  gn_apply_kernel<<<512, 256, 0, stream>>>(st2, stats, gamma, beta, out);
}

// Round 3
// 737.519 us; speedup vs baseline: 1.4883x; 1.1618x over previous
//
#include <hip/hip_runtime.h>
#include <math.h>

// SpaMamba: row-mamba (scan along W) -> col-mamba (scan along H) -> GroupNorm+SiLU
// B=8, C=128, H=64, W=64, D_INNER=256, D_STATE=16, D_CONV=4, DT_RANK=8, GROUPS=4
//
// Position index n (15 bits) decomposes as b[3] : m1[6] : m0[6].
// Row phase:  m1=h, m0=w (seq = b*64+h, t=w).  Col phase: m1=w, m0=h (seq=b*64+w, t=h).
//
// Workspace layout (floats):
//   xz    : 32768*512  = 16,777,216   (xc_pre | z)
//   xc    : 32768*256  =  8,388,608   (post-conv silu)   [stage2 overlays this in col phase]
//   dt    : 32768*256  =  8,388,608   (dt; scan overwrites in place with y*silu(z))
//   st1   : 32768*128  =  4,194,304   (row-mamba output (B,H,W,C); ALSO aliased by
//                                      xdbl (32768*40) in the window where st1 is dead)
//   stats : 64
//   partials: 2048*2 doubles (GN two-stage reduction)
// total ~151 MB

#define SILU(x) ((x) / (1.f + expf(-(x))))

// ---------------- generic tiled fp32 GEMM:  C[n][j] = sum_k A[n,k] * W[j*K+k] ----------
// A[n,k] addressed via  b*SB + m1*S1 + m0*S0 + k*SK  with n = (b<<12)|(m1<<6)|m0.
// NJ = number of valid output columns (W rows); NO = row stride of C.
__global__ __launch_bounds__(256) void gemm_kernel(
    const float* __restrict__ A, const float* __restrict__ Wm, float* __restrict__ Cc,
    int NO, int NJ, int K, int SB, int S1, int S0, int SK, int KCONTIG) {
  __shared__ __align__(16) float At[64][68];   // [k][n]
  __shared__ __align__(16) float Ws[64][68];   // [k][j]
  const int tid = threadIdx.x;
  const int n0 = blockIdx.x * 64;
  const int j0 = blockIdx.y * 64;
  const int ti = tid >> 4, tj = tid & 15;     // 16x16 thread tile, each 4x4 outputs
  const int p0 = ti * 4, q0 = tj * 4;

  float acc[4][4];
#pragma unroll
  for (int i = 0; i < 4; i++)
#pragma unroll
    for (int q = 0; q < 4; q++) acc[i][q] = 0.f;

  for (int kc = 0; kc < K; kc += 64) {
    // load A tile (64 n x 64 k), transposed into At[k][n]
#pragma unroll
    for (int i = 0; i < 16; i++) {
      int idx = tid + i * 256;
      int k_l, n_l;
      if (KCONTIG) { k_l = idx & 63; n_l = idx >> 6; }
      else         { n_l = idx & 63; k_l = idx >> 6; }
      int n = n0 + n_l;
      int b = n >> 12, m1 = (n >> 6) & 63, m0 = n & 63;
      At[k_l][n_l] = A[b * SB + m1 * S1 + m0 * S0 + (kc + k_l) * SK];
    }
    // load W tile (64 j x 64 k), transposed into Ws[k][j]; guard j >= NJ
#pragma unroll
    for (int i = 0; i < 16; i++) {
      int idx = tid + i * 256;
      int k_l = idx & 63, j_l = idx >> 6;
      Ws[k_l][j_l] = (j0 + j_l < NJ) ? Wm[(j0 + j_l) * K + kc + k_l] : 0.f;
    }
    __syncthreads();
#pragma unroll 16
    for (int k = 0; k < 64; k++) {
      float4 a4 = *reinterpret_cast<const float4*>(&At[k][p0]);
      float4 b4 = *reinterpret_cast<const float4*>(&Ws[k][q0]);
      const float av[4] = {a4.x, a4.y, a4.z, a4.w};
      const float bv[4] = {b4.x, b4.y, b4.z, b4.w};
#pragma unroll
      for (int i = 0; i < 4; i++)
#pragma unroll
        for (int q = 0; q < 4; q++) acc[i][q] = fmaf(av[i], bv[q], acc[i][q]);
    }
    __syncthreads();
  }
  if (j0 + q0 < NJ) {
#pragma unroll
    for (int i = 0; i < 4; i++) {
      float4 v = make_float4(acc[i][0], acc[i][1], acc[i][2], acc[i][3]);
      *reinterpret_cast<float4*>(&Cc[(n0 + p0 + i) * NO + j0 + q0]) = v;
    }
  }
}

// ---------------- causal depthwise conv (k=4) + bias + silu -----------------
__global__ __launch_bounds__(256) void conv_silu_kernel(
    const float* __restrict__ xz, const float* __restrict__ cw,
    const float* __restrict__ cb, float* __restrict__ xc) {
  int n = blockIdx.x;          // position
  int d = threadIdx.x;         // channel 0..255
  int w = n & 63;              // t within sequence
  float acc = cb[d];
  const float* cwd = cw + d * 4;
#pragma unroll
  for (int k = 0; k < 4; k++) {
    int ws = w - 3 + k;
    if (ws >= 0) acc = fmaf(xz[(n - 3 + k) * 512 + d], cwd[k], acc);
  }
  xc[n * 256 + d] = SILU(acc);
}

// ---------------- dt expansion: dt = softplus(xdbl[:, :8] @ Wdt.T + bdt) -----------
__global__ __launch_bounds__(256) void dt_expand_kernel(
    const float* __restrict__ xdbl, const float* __restrict__ Wdt,
    const float* __restrict__ bdt, float* __restrict__ dt) {
  __shared__ float lx[64][8];
  int n0 = blockIdx.x * 64, t = threadIdx.x;
#pragma unroll
  for (int i = 0; i < 2; i++) {
    int idx = t + i * 256;
    int n = idx >> 3, r = idx & 7;
    lx[n][r] = xdbl[(n0 + n) * 40 + r];
  }
  float w[8];
#pragma unroll
  for (int r = 0; r < 8; r++) w[r] = Wdt[t * 8 + r];
  float bb = bdt[t];
  __syncthreads();
  for (int n = 0; n < 64; n++) {
    float acc = bb;
#pragma unroll
    for (int r = 0; r < 8; r++) acc = fmaf(lx[n][r], w[r], acc);
    dt[(n0 + n) * 256 + t] = fmaxf(acc, 0.f) + log1pf(expf(-fabsf(acc)));
  }
}

// ---------------- sequential SSM scan, one thread per (seq, d) ----------------
// writes ydt[idx] = (y + xc*D) * silu(z)  in place over dt (read-before-write per thread)
// B/C come straight from xdbl rows: B = xdbl[n][8:24], C = xdbl[n][24:40]
__global__ __launch_bounds__(256) void scan_kernel(
    const float* dtb, const float* __restrict__ xcb, const float* __restrict__ xzb,
    const float* __restrict__ xdbl, const float* __restrict__ Alog,
    const float* __restrict__ Dv, float* ydt) {
  __shared__ float lbc[64 * 32];
  int seq = blockIdx.x, d = threadIdx.x;
  int base = seq * 64;
#pragma unroll
  for (int i = 0; i < 8; i++) {
    int idx = d + i * 256;
    int w = idx >> 5, s = idx & 31;
    lbc[idx] = xdbl[(base + w) * 40 + 8 + s];
  }
  float As[16];
#pragma unroll
  for (int s = 0; s < 16; s++) As[s] = -expf(Alog[d * 16 + s]);
  float Dd = Dv[d];
  float h[16];
#pragma unroll
  for (int s = 0; s < 16; s++) h[s] = 0.f;
  __syncthreads();
  for (int w = 0; w < 64; w++) {
    int idx = (base + w) * 256 + d;
    float dtv = dtb[idx];
    float xcv = xcb[idx];
    float dx = dtv * xcv;
    float yv = 0.f;
    const float* bw = lbc + w * 32;
#pragma unroll
    for (int s = 0; s < 16; s++) {
      h[s] = fmaf(h[s], expf(dtv * As[s]), dx * bw[s]);
      yv = fmaf(h[s], bw[16 + s], yv);
    }
    float zv = xzb[(base + w) * 512 + 256 + d];
    ydt[idx] = (yv + xcv * Dd) * SILU(zv);
  }
}

// ---------------- GroupNorm stats, two-stage ----------------
// stage 1: 2048 blocks = 64 per (b,g); each reduces 2048 elements (64 spatial x 32 ch)
__global__ __launch_bounds__(256) void gn_partial_kernel(
    const float* __restrict__ s2, double* __restrict__ partials) {
  int bg = blockIdx.x >> 6, sub = blockIdx.x & 63;
  int b = bg >> 2, g = bg & 3;
  int t = threadIdx.x;
  const float* basep = s2 + b * 524288 + g * 32 + sub * 64 * 128;  // 64 spatial rows
  double sum = 0.0, sumsq = 0.0;
#pragma unroll
  for (int i = 0; i < 8; i++) {
    int idx = t + i * 256;           // 0..2047
    int c = idx & 31, sp = idx >> 5; // sp in 0..63
    float v = basep[sp * 128 + c];
    sum += v;
    sumsq += (double)v * v;
  }
  __shared__ double ls[256], lq[256];
  ls[t] = sum; lq[t] = sumsq;
  __syncthreads();
  for (int o = 128; o > 0; o >>= 1) {
    if (t < o) { ls[t] += ls[t + o]; lq[t] += lq[t + o]; }
    __syncthreads();
  }
  if (t == 0) {
    partials[blockIdx.x * 2]     = ls[0];
    partials[blockIdx.x * 2 + 1] = lq[0];
  }
}

// stage 2: 32 blocks (one per (b,g)) x 64 threads; reduce 64 partial pairs
__global__ __launch_bounds__(64) void gn_final_kernel(
    const double* __restrict__ partials, float* __restrict__ stats) {
  int bg = blockIdx.x, t = threadIdx.x;
  __shared__ double ls[64], lq[64];
  ls[t] = partials[(bg * 64 + t) * 2];
  lq[t] = partials[(bg * 64 + t) * 2 + 1];
  __syncthreads();
  for (int o = 32; o > 0; o >>= 1) {
    if (t < o) { ls[t] += ls[t + o]; lq[t] += lq[t + o]; }
    __syncthreads();
  }
  if (t == 0) {
    double mu = ls[0] / 131072.0;
    double var = lq[0] / 131072.0 - mu * mu;
    stats[bg * 2] = (float)mu;
    stats[bg * 2 + 1] = (float)(1.0 / sqrt(var + 1e-5));
  }
}

// ---------------- GN apply + silu, with LDS transpose (b,w,h,c) -> (b,c,h,w) --------
__global__ __launch_bounds__(256) void gn_apply_kernel(
    const float* __restrict__ s2, const float* __restrict__ stats,
    const float* __restrict__ gamma, const float* __restrict__ beta,
    float* __restrict__ out) {
  __shared__ float tile[64 * 129];  // [w][c], pad to 129 to kill bank conflicts
  int b = blockIdx.x >> 6, hh = blockIdx.x & 63;
  int t = threadIdx.x;
  const float* src = s2 + b * 524288 + hh * 128;  // + w*8192 + c
#pragma unroll
  for (int i = 0; i < 32; i++) {
    int idx = t + i * 256;
    int c = idx & 127, w = idx >> 7;
    tile[w * 129 + c] = src[w * 8192 + c];
  }
  __syncthreads();
  float* dst = out + b * 524288 + hh * 64;        // + c*4096 + w
#pragma unroll
  for (int i = 0; i < 32; i++) {
    int idx = t + i * 256;
    int w = idx & 63, c = idx >> 6;
    int g = c >> 5;
    float mu = stats[(b * 4 + g) * 2];
    float rs = stats[(b * 4 + g) * 2 + 1];
    float v = fmaf((tile[w * 129 + c] - mu) * rs, gamma[c], beta[c]);
    dst[c * 4096 + w] = SILU(v);
  }
}

extern "C" void kernel_launch(void* const* d_in, const int* in_sizes, int n_in,
                              void* d_out, int out_size, void* d_ws, size_t ws_size,
                              hipStream_t stream) {
  const float* x = (const float*)d_in[0];
  // row weights
  const float* rWin  = (const float*)d_in[1];
  const float* rcw   = (const float*)d_in[2];
  const float* rcb   = (const float*)d_in[3];
  const float* rWx   = (const float*)d_in[4];
  const float* rWdt  = (const float*)d_in[5];
  const float* rbdt  = (const float*)d_in[6];
  const float* rAlog = (const float*)d_in[7];
  const float* rD    = (const float*)d_in[8];
  const float* rWout = (const float*)d_in[9];
  // col weights
  const float* cWin  = (const float*)d_in[10];
  const float* ccw   = (const float*)d_in[11];
  const float* ccb   = (const float*)d_in[12];
  const float* cWx   = (const float*)d_in[13];
  const float* cWdt  = (const float*)d_in[14];
  const float* cbdt  = (const float*)d_in[15];
  const float* cAlog = (const float*)d_in[16];
  const float* cD    = (const float*)d_in[17];
  const float* cWout = (const float*)d_in[18];
  const float* gamma = (const float*)d_in[19];
  const float* beta  = (const float*)d_in[20];
  float* out = (float*)d_out;

  float* ws = (float*)d_ws;
  float* xz    = ws;                    // 16,777,216
  float* xc    = xz  + 16777216;        //  8,388,608
  float* dt    = xc  + 8388608;         //  8,388,608
  float* st1   = dt  + 8388608;         //  4,194,304
  float* stats = st1 + 4194304;         //  64
  double* partials = (double*)(stats + 64);   // 2048*2 doubles (8-byte aligned)
  float* xdbl  = st1;                   // overlay: st1 is dead while xdbl lives
  float* st2   = xc;                    // overlay: xc is dead by the time stage2 is written

  auto run_mamba = [&](const float* A, int SB, int S1, int S0, int SK, int KCONTIG,
                       const float* Win, const float* cw, const float* cb,
                       const float* Wx, const float* Wdt, const float* bdt,
                       const float* Alog, const float* Dv, const float* Wout,
                       float* outp) {
    gemm_kernel<<<dim3(512, 8), 256, 0, stream>>>(A, Win, xz, 512, 512, 128,
                                                  SB, S1, S0, SK, KCONTIG);
    conv_silu_kernel<<<32768, 256, 0, stream>>>(xz, cw, cb, xc);
    // xdbl = xc @ Wx.T   (M=32768, N=40, K=256); xc is n-major contiguous
    gemm_kernel<<<dim3(512, 1), 256, 0, stream>>>(xc, Wx, xdbl, 40, 40, 256,
                                                  1048576, 16384, 256, 1, 1);
    dt_expand_kernel<<<512, 256, 0, stream>>>(xdbl, Wdt, bdt, dt);
    scan_kernel<<<512, 256, 0, stream>>>(dt, xc, xz, xdbl, Alog, Dv, dt);
    gemm_kernel<<<dim3(512, 2), 256, 0, stream>>>(dt, Wout, outp, 128, 128, 256,
                                                  1048576, 16384, 256, 1, 1);
  };

  // row phase: A[n,k] = x[b,k,h,w], n=(b,h,w)
  run_mamba(x, 524288, 64, 1, 4096, 0,
            rWin, rcw, rcb, rWx, rWdt, rbdt, rAlog, rD, rWout, st1);
  // col phase: A[n,k] = st1[b,h,w,k], n=(b,w,h)
  run_mamba(st1, 524288, 128, 8192, 1, 1,
            cWin, ccw, ccb, cWx, cWdt, cbdt, cAlog, cD, cWout, st2);

  gn_partial_kernel<<<2048, 256, 0, stream>>>(st2, partials);
  gn_final_kernel<<<32, 64, 0, stream>>>(partials, stats);
  gn_apply_kernel<<<512, 256, 0, stream>>>(st2, stats, gamma, beta, out);
}

// Round 4
// 551.890 us; speedup vs baseline: 1.9889x; 1.3364x over previous
//
#include <hip/hip_runtime.h>
#include <math.h>

// SpaMamba: row-mamba (scan along W) -> col-mamba (scan along H) -> GroupNorm+SiLU
// B=8, C=128, H=64, W=64, D_INNER=256, D_STATE=16, D_CONV=4, DT_RANK=8, GROUPS=4
//
// GEMMs now run on the matrix pipe via split-bf16 (hi+lo) x3 MFMA:
//   a*b ~= hi(a)hi(b) + hi(a)lo(b) + lo(a)hi(b), fp32 accumulation.
// Truncation split: |a - hi - lo| <= 2^-16 |a|  -> ~1e-4 end-to-end absmax.

#define SILU(x) ((x) / (1.f + expf(-(x))))

typedef __attribute__((ext_vector_type(8))) short short8v;
typedef __attribute__((ext_vector_type(16))) float floatx16;

__device__ inline unsigned f32bits(float x) { return __builtin_bit_cast(unsigned, x); }
__device__ inline float bits32f(unsigned x) { return __builtin_bit_cast(float, x); }

// ---------------- MFMA split-bf16 GEMM:  C[n][j] = sum_k A[n,k] * W[j*K+k] ----------
// A[n,k] addressed via  b*SB + m1*S1 + m0*S0 + k*SK  with n = (b<<12)|(m1<<6)|m0.
// Block tile: 128 (M) x NT (N), 4 waves. Wave tile 64 x NT/2.
// LDS rows: 32 k-elements bf16 + 8 pad = 40 shorts = 80 B (16B aligned, conflict-free
// for the 32x32x16 fragment read pattern: exactly 8 accesses/bank).
template <int NT>
__global__ __launch_bounds__(256) void mfma_gemm(
    const float* __restrict__ A, const float* __restrict__ Wm, float* __restrict__ Cc,
    int NO, int NJ, int K, int SB, int S1, int S0, int SK, int KCONTIG) {
  __shared__ __align__(16) short Ah[128][40];
  __shared__ __align__(16) short Al[128][40];
  __shared__ __align__(16) short Wh[NT][40];
  __shared__ __align__(16) short Wl[NT][40];

  const int tid = threadIdx.x;
  const int lane = tid & 63, wave = tid >> 6;
  const int n0 = blockIdx.x * 128;
  const int j0 = blockIdx.y * NT;
  constexpr int NTW = NT / 2;        // per-wave n extent: 64 or 32
  constexpr int NSUB = NTW / 32;     // n subtiles per wave: 2 or 1
  const int m_wave = (wave & 1) * 64;
  const int n_wave = (wave >> 1) * NTW;

  floatx16 acc[2][NSUB];
#pragma unroll
  for (int mt = 0; mt < 2; mt++)
#pragma unroll
    for (int nt = 0; nt < NSUB; nt++)
#pragma unroll
      for (int r = 0; r < 16; r++) acc[mt][nt][r] = 0.f;

  // staging thread->element maps
  int mA, ksA;
  if (KCONTIG) { mA = tid >> 1; ksA = (tid & 1) * 16; }
  else         { mA = tid & 127; ksA = (tid >> 7) * 16; }
  const int nA = n0 + mA;
  const int bA = nA >> 12, m1A = (nA >> 6) & 63, m0A = nA & 63;
  const float* aRow = A + (size_t)bA * SB + (size_t)m1A * S1 + (size_t)m0A * S0;
  const int jW = tid >> 1, ksW = (tid & 1) * 16;

  const int half = lane >> 5;        // k-half selector for fragments
  const int lrow = lane & 31;

  for (int kc = 0; kc < K; kc += 32) {
    // ---- stage A (fp32 -> hi/lo bf16) ----
    float v[16];
    if (KCONTIG) {
      const float4* p4 = (const float4*)(aRow + kc + ksA);
#pragma unroll
      for (int q = 0; q < 4; q++) {
        float4 t = p4[q];
        v[q * 4 + 0] = t.x; v[q * 4 + 1] = t.y; v[q * 4 + 2] = t.z; v[q * 4 + 3] = t.w;
      }
    } else {
      const float* p = aRow + (size_t)(kc + ksA) * SK;
#pragma unroll
      for (int i = 0; i < 16; i++) v[i] = p[(size_t)i * SK];
    }
    unsigned uh[8], ul[8];
#pragma unroll
    for (int i = 0; i < 8; i++) {
      unsigned a0 = f32bits(v[2 * i]), a1 = f32bits(v[2 * i + 1]);
      uh[i] = __builtin_amdgcn_perm(a1, a0, 0x07060302);
      float l0 = v[2 * i] - bits32f(a0 & 0xFFFF0000u);
      float l1 = v[2 * i + 1] - bits32f(a1 & 0xFFFF0000u);
      ul[i] = __builtin_amdgcn_perm(f32bits(l1), f32bits(l0), 0x07060302);
    }
    {
      char* dh = (char*)Ah + (size_t)mA * 80 + ksA * 2;
      char* dl = (char*)Al + (size_t)mA * 80 + ksA * 2;
      ((uint4*)dh)[0] = make_uint4(uh[0], uh[1], uh[2], uh[3]);
      ((uint4*)dh)[1] = make_uint4(uh[4], uh[5], uh[6], uh[7]);
      ((uint4*)dl)[0] = make_uint4(ul[0], ul[1], ul[2], ul[3]);
      ((uint4*)dl)[1] = make_uint4(ul[4], ul[5], ul[6], ul[7]);
    }
    // ---- stage W ----
    if (jW < NT) {
      float wv[16];
      if (j0 + jW < NJ) {
        const float4* p4 = (const float4*)(Wm + (size_t)(j0 + jW) * K + kc + ksW);
#pragma unroll
        for (int q = 0; q < 4; q++) {
          float4 t = p4[q];
          wv[q * 4 + 0] = t.x; wv[q * 4 + 1] = t.y; wv[q * 4 + 2] = t.z; wv[q * 4 + 3] = t.w;
        }
      } else {
#pragma unroll
        for (int i = 0; i < 16; i++) wv[i] = 0.f;
      }
      unsigned wh[8], wl[8];
#pragma unroll
      for (int i = 0; i < 8; i++) {
        unsigned a0 = f32bits(wv[2 * i]), a1 = f32bits(wv[2 * i + 1]);
        wh[i] = __builtin_amdgcn_perm(a1, a0, 0x07060302);
        float l0 = wv[2 * i] - bits32f(a0 & 0xFFFF0000u);
        float l1 = wv[2 * i + 1] - bits32f(a1 & 0xFFFF0000u);
        wl[i] = __builtin_amdgcn_perm(f32bits(l1), f32bits(l0), 0x07060302);
      }
      char* dh = (char*)Wh + (size_t)jW * 80 + ksW * 2;
      char* dl = (char*)Wl + (size_t)jW * 80 + ksW * 2;
      ((uint4*)dh)[0] = make_uint4(wh[0], wh[1], wh[2], wh[3]);
      ((uint4*)dh)[1] = make_uint4(wh[4], wh[5], wh[6], wh[7]);
      ((uint4*)dl)[0] = make_uint4(wl[0], wl[1], wl[2], wl[3]);
      ((uint4*)dl)[1] = make_uint4(wl[4], wl[5], wl[6], wl[7]);
    }
    __syncthreads();

    // ---- compute: 2 k16 steps ----
#pragma unroll
    for (int s = 0; s < 2; s++) {
      const int koff = s * 32 + half * 16;   // byte offset into 80B row
      short8v afh[2], afl[2], wfh[NSUB], wfl[NSUB];
#pragma unroll
      for (int mt = 0; mt < 2; mt++) {
        int mr = m_wave + mt * 32 + lrow;
        afh[mt] = *(const short8v*)((const char*)Ah + (size_t)mr * 80 + koff);
        afl[mt] = *(const short8v*)((const char*)Al + (size_t)mr * 80 + koff);
      }
#pragma unroll
      for (int nt = 0; nt < NSUB; nt++) {
        int nr = n_wave + nt * 32 + lrow;
        wfh[nt] = *(const short8v*)((const char*)Wh + (size_t)nr * 80 + koff);
        wfl[nt] = *(const short8v*)((const char*)Wl + (size_t)nr * 80 + koff);
      }
#pragma unroll
      for (int mt = 0; mt < 2; mt++)
#pragma unroll
        for (int nt = 0; nt < NSUB; nt++) {
          acc[mt][nt] = __builtin_amdgcn_mfma_f32_32x32x16_bf16(afh[mt], wfh[nt], acc[mt][nt], 0, 0, 0);
          acc[mt][nt] = __builtin_amdgcn_mfma_f32_32x32x16_bf16(afh[mt], wfl[nt], acc[mt][nt], 0, 0, 0);
          acc[mt][nt] = __builtin_amdgcn_mfma_f32_32x32x16_bf16(afl[mt], wfh[nt], acc[mt][nt], 0, 0, 0);
        }
    }
    __syncthreads();
  }

  // ---- epilogue: C/D layout col=lane&31, row=(r&3)+8*(r>>2)+4*(lane>>5) ----
#pragma unroll
  for (int mt = 0; mt < 2; mt++)
#pragma unroll
    for (int nt = 0; nt < NSUB; nt++) {
      int col = j0 + n_wave + nt * 32 + lrow;
      if (col < NJ) {
#pragma unroll
        for (int r = 0; r < 16; r++) {
          int row = n0 + m_wave + mt * 32 + (r & 3) + 8 * (r >> 2) + 4 * half;
          Cc[(size_t)row * NO + col] = acc[mt][nt][r];
        }
      }
    }
}

// ---------------- causal depthwise conv (k=4) + bias + silu -----------------
__global__ __launch_bounds__(256) void conv_silu_kernel(
    const float* __restrict__ xz, const float* __restrict__ cw,
    const float* __restrict__ cb, float* __restrict__ xc) {
  int n = blockIdx.x;          // position
  int d = threadIdx.x;         // channel 0..255
  int w = n & 63;              // t within sequence
  float acc = cb[d];
  const float* cwd = cw + d * 4;
#pragma unroll
  for (int k = 0; k < 4; k++) {
    int ws = w - 3 + k;
    if (ws >= 0) acc = fmaf(xz[(n - 3 + k) * 512 + d], cwd[k], acc);
  }
  xc[n * 256 + d] = SILU(acc);
}

// ---------------- dt expansion: dt = softplus(xdbl[:, :8] @ Wdt.T + bdt) -----------
__global__ __launch_bounds__(256) void dt_expand_kernel(
    const float* __restrict__ xdbl, const float* __restrict__ Wdt,
    const float* __restrict__ bdt, float* __restrict__ dt) {
  __shared__ float lx[64][8];
  int n0 = blockIdx.x * 64, t = threadIdx.x;
#pragma unroll
  for (int i = 0; i < 2; i++) {
    int idx = t + i * 256;
    int n = idx >> 3, r = idx & 7;
    lx[n][r] = xdbl[(n0 + n) * 40 + r];
  }
  float w[8];
#pragma unroll
  for (int r = 0; r < 8; r++) w[r] = Wdt[t * 8 + r];
  float bb = bdt[t];
  __syncthreads();
  for (int n = 0; n < 64; n++) {
    float acc = bb;
#pragma unroll
    for (int r = 0; r < 8; r++) acc = fmaf(lx[n][r], w[r], acc);
    dt[(n0 + n) * 256 + t] = fmaxf(acc, 0.f) + log1pf(expf(-fabsf(acc)));
  }
}

// ---------------- sequential SSM scan, one thread per (seq, d) ----------------
__global__ __launch_bounds__(256) void scan_kernel(
    const float* dtb, const float* __restrict__ xcb, const float* __restrict__ xzb,
    const float* __restrict__ xdbl, const float* __restrict__ Alog,
    const float* __restrict__ Dv, float* ydt) {
  __shared__ float lbc[64 * 32];
  int seq = blockIdx.x, d = threadIdx.x;
  int base = seq * 64;
#pragma unroll
  for (int i = 0; i < 8; i++) {
    int idx = d + i * 256;
    int w = idx >> 5, s = idx & 31;
    lbc[idx] = xdbl[(base + w) * 40 + 8 + s];
  }
  float As[16];
#pragma unroll
  for (int s = 0; s < 16; s++) As[s] = -expf(Alog[d * 16 + s]);
  float Dd = Dv[d];
  float h[16];
#pragma unroll
  for (int s = 0; s < 16; s++) h[s] = 0.f;
  __syncthreads();
  for (int w = 0; w < 64; w++) {
    int idx = (base + w) * 256 + d;
    float dtv = dtb[idx];
    float xcv = xcb[idx];
    float dx = dtv * xcv;
    float yv = 0.f;
    const float* bw = lbc + w * 32;
#pragma unroll
    for (int s = 0; s < 16; s++) {
      h[s] = fmaf(h[s], expf(dtv * As[s]), dx * bw[s]);
      yv = fmaf(h[s], bw[16 + s], yv);
    }
    float zv = xzb[(base + w) * 512 + 256 + d];
    ydt[idx] = (yv + xcv * Dd) * SILU(zv);
  }
}

// ---------------- GroupNorm stats, two-stage ----------------
__global__ __launch_bounds__(256) void gn_partial_kernel(
    const float* __restrict__ s2, double* __restrict__ partials) {
  int bg = blockIdx.x >> 6, sub = blockIdx.x & 63;
  int b = bg >> 2, g = bg & 3;
  int t = threadIdx.x;
  const float* basep = s2 + b * 524288 + g * 32 + sub * 64 * 128;
  double sum = 0.0, sumsq = 0.0;
#pragma unroll
  for (int i = 0; i < 8; i++) {
    int idx = t + i * 256;
    int c = idx & 31, sp = idx >> 5;
    float v = basep[sp * 128 + c];
    sum += v;
    sumsq += (double)v * v;
  }
  __shared__ double ls[256], lq[256];
  ls[t] = sum; lq[t] = sumsq;
  __syncthreads();
  for (int o = 128; o > 0; o >>= 1) {
    if (t < o) { ls[t] += ls[t + o]; lq[t] += lq[t + o]; }
    __syncthreads();
  }
  if (t == 0) {
    partials[blockIdx.x * 2]     = ls[0];
    partials[blockIdx.x * 2 + 1] = lq[0];
  }
}

__global__ __launch_bounds__(64) void gn_final_kernel(
    const double* __restrict__ partials, float* __restrict__ stats) {
  int bg = blockIdx.x, t = threadIdx.x;
  __shared__ double ls[64], lq[64];
  ls[t] = partials[(bg * 64 + t) * 2];
  lq[t] = partials[(bg * 64 + t) * 2 + 1];
  __syncthreads();
  for (int o = 32; o > 0; o >>= 1) {
    if (t < o) { ls[t] += ls[t + o]; lq[t] += lq[t + o]; }
    __syncthreads();
  }
  if (t == 0) {
    double mu = ls[0] / 131072.0;
    double var = lq[0] / 131072.0 - mu * mu;
    stats[bg * 2] = (float)mu;
    stats[bg * 2 + 1] = (float)(1.0 / sqrt(var + 1e-5));
  }
}

// ---------------- GN apply + silu, with LDS transpose (b,w,h,c) -> (b,c,h,w) --------
__global__ __launch_bounds__(256) void gn_apply_kernel(
    const float* __restrict__ s2, const float* __restrict__ stats,
    const float* __restrict__ gamma, const float* __restrict__ beta,
    float* __restrict__ out) {
  __shared__ float tile[64 * 129];
  int b = blockIdx.x >> 6, hh = blockIdx.x & 63;
  int t = threadIdx.x;
  const float* src = s2 + b * 524288 + hh * 128;
#pragma unroll
  for (int i = 0; i < 32; i++) {
    int idx = t + i * 256;
    int c = idx & 127, w = idx >> 7;
    tile[w * 129 + c] = src[w * 8192 + c];
  }
  __syncthreads();
  float* dst = out + b * 524288 + hh * 64;
#pragma unroll
  for (int i = 0; i < 32; i++) {
    int idx = t + i * 256;
    int w = idx & 63, c = idx >> 6;
    int g = c >> 5;
    float mu = stats[(b * 4 + g) * 2];
    float rs = stats[(b * 4 + g) * 2 + 1];
    float v = fmaf((tile[w * 129 + c] - mu) * rs, gamma[c], beta[c]);
    dst[c * 4096 + w] = SILU(v);
  }
}

extern "C" void kernel_launch(void* const* d_in, const int* in_sizes, int n_in,
                              void* d_out, int out_size, void* d_ws, size_t ws_size,
                              hipStream_t stream) {
  const float* x = (const float*)d_in[0];
  const float* rWin  = (const float*)d_in[1];
  const float* rcw   = (const float*)d_in[2];
  const float* rcb   = (const float*)d_in[3];
  const float* rWx   = (const float*)d_in[4];
  const float* rWdt  = (const float*)d_in[5];
  const float* rbdt  = (const float*)d_in[6];
  const float* rAlog = (const float*)d_in[7];
  const float* rD    = (const float*)d_in[8];
  const float* rWout = (const float*)d_in[9];
  const float* cWin  = (const float*)d_in[10];
  const float* ccw   = (const float*)d_in[11];
  const float* ccb   = (const float*)d_in[12];
  const float* cWx   = (const float*)d_in[13];
  const float* cWdt  = (const float*)d_in[14];
  const float* cbdt  = (const float*)d_in[15];
  const float* cAlog = (const float*)d_in[16];
  const float* cD    = (const float*)d_in[17];
  const float* cWout = (const float*)d_in[18];
  const float* gamma = (const float*)d_in[19];
  const float* beta  = (const float*)d_in[20];
  float* out = (float*)d_out;

  float* ws = (float*)d_ws;
  float* xz    = ws;                    // 16,777,216
  float* xc    = xz  + 16777216;        //  8,388,608
  float* dt    = xc  + 8388608;         //  8,388,608
  float* st1   = dt  + 8388608;         //  4,194,304
  float* stats = st1 + 4194304;         //  64
  double* partials = (double*)(stats + 64);
  float* xdbl  = st1;                   // overlay: st1 dead while xdbl lives
  float* st2   = xc;                    // overlay: xc dead when stage2 written

  auto run_mamba = [&](const float* A, int SB, int S1, int S0, int SK, int KCONTIG,
                       const float* Win, const float* cw, const float* cb,
                       const float* Wx, const float* Wdt, const float* bdt,
                       const float* Alog, const float* Dv, const float* Wout,
                       float* outp) {
    mfma_gemm<128><<<dim3(256, 4), 256, 0, stream>>>(A, Win, xz, 512, 512, 128,
                                                     SB, S1, S0, SK, KCONTIG);
    conv_silu_kernel<<<32768, 256, 0, stream>>>(xz, cw, cb, xc);
    mfma_gemm<64><<<dim3(256, 1), 256, 0, stream>>>(xc, Wx, xdbl, 40, 40, 256,
                                                    1048576, 16384, 256, 1, 1);
    dt_expand_kernel<<<512, 256, 0, stream>>>(xdbl, Wdt, bdt, dt);
    scan_kernel<<<512, 256, 0, stream>>>(dt, xc, xz, xdbl, Alog, Dv, dt);
    mfma_gemm<128><<<dim3(256, 1), 256, 0, stream>>>(dt, Wout, outp, 128, 128, 256,
                                                     1048576, 16384, 256, 1, 1);
  };

  // row phase: A[n,k] = x[b,k,h,w], n=(b,h,w)
  run_mamba(x, 524288, 64, 1, 4096, 0,
            rWin, rcw, rcb, rWx, rWdt, rbdt, rAlog, rD, rWout, st1);
  // col phase: A[n,k] = st1[b,h,w,k], n=(b,w,h)
  run_mamba(st1, 524288, 128, 8192, 1, 1,
            cWin, ccw, ccb, cWx, cWdt, cbdt, cAlog, cD, cWout, st2);

  gn_partial_kernel<<<2048, 256, 0, stream>>>(st2, partials);
  gn_final_kernel<<<32, 64, 0, stream>>>(partials, stats);
  gn_apply_kernel<<<512, 256, 0, stream>>>(st2, stats, gamma, beta, out);
}